// Round 12
// baseline (393.149 us; speedup 1.0000x reference)
//
#include <hip/hip_runtime.h>
#include <math.h>

#define NN 100000
#define NE 1600000
#define NPB 256                     // nodes per bucket (dst >> 8)
#define NB 391                      // ceil(NN / NPB)
#define NCHUNK 512                  // binning chunks
#define CH 3125                     // NE / NCHUNK (exact)
#define SEGW (NB + 1)               // seg table row width
#define MAXB 5376                   // max records per bucket (mean 4096, +20 sigma)
#define LOG2E 1.44269504088896f

typedef __attribute__((ext_vector_type(8))) short bf16x8;
typedef __attribute__((ext_vector_type(4))) float f32x4;

__device__ __forceinline__ float lrelu(float x) { return fmaxf(x, 0.2f * x); }
__device__ __forceinline__ float elu1(float x) { return x > 0.f ? x : (__expf(x) - 1.f); }
__device__ __forceinline__ float fexp2(float x) {
#if __has_builtin(__builtin_amdgcn_exp2f)
    return __builtin_amdgcn_exp2f(x);
#else
    return exp2f(x);
#endif
}
__device__ __forceinline__ unsigned bf16rne(float f) {
    unsigned u = __float_as_uint(f);
    return (u + 0x7FFFu + ((u >> 16) & 1u)) >> 16;
}
__device__ __forceinline__ float bf16lo(unsigned u) { return __uint_as_float(u << 16); }
__device__ __forceinline__ float bf16hi(unsigned u) {
    return __uint_as_float(u & 0xFFFF0000u);
}

// ================= binned CSR build =================
// bin1: chunk-per-block. Sort chunk's records by bucket IN LDS, flush coalesced
// chunk-major. Emits per-chunk segment table + global bucket counts.
__global__ void __launch_bounds__(256) k_bin1(const int* __restrict__ src,
                                              const int* __restrict__ dst,
                                              const float* __restrict__ ea,
                                              int* __restrict__ bucket_cnt,
                                              int* __restrict__ seg,
                                              uint2* __restrict__ binned,
                                              unsigned char* __restrict__ dstb) {
    __shared__ int hist[NB], start[NB], cur[NB];
    __shared__ int s2[256];
    __shared__ uint2 stage[CH];
    __shared__ unsigned char dstg[CH];
    int c = blockIdx.x, t = threadIdx.x;
    int e0 = c * CH;
    for (int b = t; b < NB; b += 256) hist[b] = 0;
    __syncthreads();
    for (int i = t; i < CH; i += 256) atomicAdd(&hist[dst[e0 + i] >> 8], 1);
    __syncthreads();
    int a0 = (2 * t < NB) ? hist[2 * t] : 0;
    int a1 = (2 * t + 1 < NB) ? hist[2 * t + 1] : 0;
    s2[t] = a0 + a1;
    __syncthreads();
    for (int off = 1; off < 256; off <<= 1) {
        int x = (t >= off) ? s2[t - off] : 0;
        __syncthreads();
        if (t >= off) s2[t] += x;
        __syncthreads();
    }
    int pex = s2[t] - (a0 + a1);
    if (2 * t < NB) { start[2 * t] = pex; cur[2 * t] = pex; }
    if (2 * t + 1 < NB) { start[2 * t + 1] = pex + a0; cur[2 * t + 1] = pex + a0; }
    __syncthreads();
    for (int b = t; b < NB; b += 256) {
        seg[c * SEGW + b] = start[b];
        if (hist[b]) atomicAdd(&bucket_cnt[b], hist[b]);
    }
    if (t == 0) seg[c * SEGW + NB] = CH;
    __syncthreads();
    for (int i = t; i < CH; i += 256) {
        int d = dst[e0 + i];
        int bkt = d >> 8;
        int p = atomicAdd(&cur[bkt], 1);
        unsigned pk = bf16rne(ea[2 * (e0 + i)]) | (bf16rne(ea[2 * (e0 + i) + 1]) << 16);
        stage[p] = make_uint2((unsigned)src[e0 + i], pk);
        dstg[p] = (unsigned char)(d & 255);
    }
    __syncthreads();
    for (int i = t; i < CH; i += 256) {
        binned[e0 + i] = stage[i];
        dstb[e0 + i] = dstg[i];
    }
}

__global__ void k_bscan(const int* __restrict__ bucket_cnt, int* __restrict__ bucket_base) {
    __shared__ int s[512];
    int t = threadIdx.x;
    int v = (t < NB) ? bucket_cnt[t] : 0;
    s[t] = v;
    __syncthreads();
    for (int off = 1; off < 512; off <<= 1) {
        int x = (t >= off) ? s[t - off] : 0;
        __syncthreads();
        if (t >= off) s[t] += x;
        __syncthreads();
    }
    if (t < NB) {
        bucket_base[t] = s[t] - v;
        if (t == NB - 1) bucket_base[NB] = s[t];
    }
}

// bin2: block-per-bucket. Gather bucket's records from chunk segments into LDS,
// then per-node counting sort -> rowptr + dst-sorted CSR + fused la.
__global__ void __launch_bounds__(256) k_bin2(const int* __restrict__ bucket_base,
                                              const int* __restrict__ seg,
                                              const uint2* __restrict__ binned,
                                              const unsigned char* __restrict__ dstb,
                                              int* __restrict__ rowptr,
                                              uint2* __restrict__ edges,
                                              float* __restrict__ la) {
    __shared__ int sstart[NCHUNK], soff[NCHUNK];
    __shared__ int s2[256];
    __shared__ uint2 stage[MAXB];
    __shared__ unsigned char sd[MAXB];
    __shared__ int hist[NPB], pre[NPB], cursor[NPB];
    __shared__ float ea0s[NPB], ea1s[NPB];
    int b = blockIdx.x, t = threadIdx.x;
    int len0, len1;
    {
        int c0 = 2 * t, c1 = 2 * t + 1;
        int st0 = seg[c0 * SEGW + b], en0 = seg[c0 * SEGW + b + 1];
        int st1 = seg[c1 * SEGW + b], en1 = seg[c1 * SEGW + b + 1];
        sstart[c0] = st0;
        sstart[c1] = st1;
        len0 = en0 - st0;
        len1 = en1 - st1;
        s2[t] = len0 + len1;
    }
    __syncthreads();
    for (int off = 1; off < 256; off <<= 1) {
        int x = (t >= off) ? s2[t - off] : 0;
        __syncthreads();
        if (t >= off) s2[t] += x;
        __syncthreads();
    }
    int pex = s2[t] - (len0 + len1);
    soff[2 * t] = pex;
    soff[2 * t + 1] = pex + len0;
    __syncthreads();
    int total = s2[255];
    if (total > MAXB) total = MAXB;
    for (int i = t; i < total; i += 256) {
        int lo = 0, hi = NCHUNK - 1;
        while (lo < hi) {
            int mid = (lo + hi + 1) >> 1;
            if (soff[mid] <= i) lo = mid; else hi = mid - 1;
        }
        int pos = lo * CH + sstart[lo] + (i - soff[lo]);
        stage[i] = binned[pos];
        sd[i] = dstb[pos];
    }
    hist[t] = 0;
    ea0s[t] = 0.f;
    ea1s[t] = 0.f;
    __syncthreads();
    for (int i = t; i < total; i += 256) atomicAdd(&hist[sd[i]], 1);
    __syncthreads();
    int v = hist[t];
    pre[t] = v;
    __syncthreads();
    for (int off = 1; off < 256; off <<= 1) {
        int x = (t >= off) ? pre[t - off] : 0;
        __syncthreads();
        if (t >= off) pre[t] += x;
        __syncthreads();
    }
    int bb = bucket_base[b];
    int ex = pre[t] - v;
    int nb0 = b << 8;
    if (nb0 + t <= NN) rowptr[nb0 + t] = bb + ex;
    cursor[t] = bb + ex;
    __syncthreads();
    for (int i = t; i < total; i += 256) {
        uint2 rec = stage[i];
        unsigned char d = sd[i];
        int pos = atomicAdd(&cursor[d], 1);
        edges[pos] = rec;
        atomicAdd(&ea0s[d], bf16lo(rec.y));
        atomicAdd(&ea1s[d], bf16hi(rec.y));
    }
    __syncthreads();
    int n = nb0 + t;
    if (n < NN) {
        float dg = fmaxf((float)v, 1.0f);
        la[2 * n] = ea0s[t] / dg;
        la[2 * n + 1] = ea1s[t] / dg;
    }
}

// ---------- fused constants: me1[8], me2[4], me3[2] (cbuf+12), vsd[40] (cbuf+16) ----------
__global__ void k_const(const float* __restrict__ We1, const float* __restrict__ aE1,
                        const float* __restrict__ We2, const float* __restrict__ aE2,
                        const float* __restrict__ We3, const float* __restrict__ aE3,
                        const float* __restrict__ W1, const float* __restrict__ aS1,
                        const float* __restrict__ aD1, float* __restrict__ cbuf) {
    int t = threadIdx.x;
    if (t < 8) {
        int d = t >> 2, hd = t & 3;
        float s = 0.f;
        for (int c = 0; c < 32; c++) s += We1[d * 128 + hd * 32 + c] * aE1[hd * 32 + c];
        cbuf[t] = s * LOG2E;
    } else if (t < 12) {
        int idx = t - 8, d = idx >> 1, hd = idx & 1;
        float s = 0.f;
        for (int c = 0; c < 32; c++) s += We2[d * 64 + hd * 32 + c] * aE2[hd * 32 + c];
        cbuf[t] = s * LOG2E;
    } else if (t < 14) {
        cbuf[t] = We3[t - 12] * aE3[0] * LOG2E;
    } else if (t >= 16 && t < 56) {
        int r = (t - 16) % 20, hd = r / 5, i = r % 5;
        const float* a = (t - 16 < 20) ? aS1 : aD1;
        float s = 0.f;
        for (int c = 0; c < 32; c++) s += W1[i * 128 + hd * 32 + c] * a[hd * 32 + c];
        cbuf[t] = s * LOG2E;
    }
}

// W2 as bf16 col-major (B-operand layout) + vS2/vD2 = W2^T aS2/aD2 (scaled)
__global__ void k_const2(const float* __restrict__ W2, const float* __restrict__ aS2,
                         const float* __restrict__ aD2, unsigned short* __restrict__ W2q,
                         float* __restrict__ vsd2) {
    int t = threadIdx.x;
    for (int x = t; x < 64 * 128; x += 256) {
        int j = x >> 7, i = x & 127;
        W2q[x] = (unsigned short)bf16rne(W2[i * 64 + j]);  // W2q[j][i]
    }
    {
        int hd = t >> 7, i = t & 127;
        float s = 0.f, d = 0.f;
        for (int c = 0; c < 32; c++) {
            float wv = W2[i * 64 + hd * 32 + c];
            s += wv * aS2[hd * 32 + c];
            d += wv * aD2[hd * 32 + c];
        }
        vsd2[t] = s * LOG2E;        // vS2[hd][i]
        vsd2[256 + t] = d * LOG2E;  // vD2[hd][i]
    }
}

// layer-1 per-node: padded x + logits als1/ald1 (scaled)
__global__ void k_prep1(const float* __restrict__ x, const float* __restrict__ vsd,
                        float4* __restrict__ xp, float4* __restrict__ als1,
                        float4* __restrict__ ald1) {
    int n = blockIdx.x * blockDim.x + threadIdx.x;
    if (n >= NN) return;
    float x0 = x[5 * n], x1 = x[5 * n + 1], x2 = x[5 * n + 2], x3 = x[5 * n + 3],
          x4 = x[5 * n + 4];
    xp[2 * n] = make_float4(x0, x1, x2, x3);
    xp[2 * n + 1] = make_float4(x4, 0.f, 0.f, 0.f);
    float sv[4], dv[4];
#pragma unroll
    for (int hd = 0; hd < 4; hd++) {
        const float* vS = vsd + hd * 5;
        const float* vD = vsd + 20 + hd * 5;
        sv[hd] = x0 * vS[0] + x1 * vS[1] + x2 * vS[2] + x3 * vS[3] + x4 * vS[4];
        dv[hd] = x0 * vD[0] + x1 * vD[1] + x2 * vD[2] + x3 * vD[3] + x4 * vD[4];
    }
    als1[n] = make_float4(sv[0], sv[1], sv[2], sv[3]);
    ald1[n] = make_float4(dv[0], dv[1], dv[2], dv[3]);
}

// ---------- layer 1 agg: thread per (node, head); single pass, m = aself ----------
__global__ void k_agg1(const int* __restrict__ rowptr, const uint2* __restrict__ edges,
                       const float4* __restrict__ xp, const float* __restrict__ als1,
                       const float* __restrict__ ald1, const float* __restrict__ la,
                       const float* __restrict__ me, float* __restrict__ xw) {
    int t = blockIdx.x * blockDim.x + threadIdx.x;
    if (t >= NN * 4) return;
    int n = t >> 2, hd = t & 3;
    float me0 = me[hd], me1 = me[4 + hd];
    float aldn = ald1[t];
    float aself = lrelu(als1[t] + aldn + la[2 * n] * me0 + la[2 * n + 1] * me1);
    int start = rowptr[n], end = rowptr[n + 1];
    float den = 1.f;
    float4 xa = xp[2 * n];
    float xb = xp[2 * n + 1].x;
    float a0 = xa.x, a1 = xa.y, a2 = xa.z, a3 = xa.w, a4 = xb;
    for (int e = start; e < end; ++e) {
        uint2 ep = edges[e];
        int s = (int)ep.x;
        float a = lrelu(als1[s * 4 + hd] + aldn + bf16lo(ep.y) * me0 + bf16hi(ep.y) * me1);
        float p = fexp2(a - aself);
        den += p;
        float4 sa = xp[2 * s];
        float sb = xp[2 * s + 1].x;
        a0 += p * sa.x;
        a1 += p * sa.y;
        a2 += p * sa.z;
        a3 += p * sa.w;
        a4 += p * sb;
    }
    float r = 1.f / den;
    float* w = xw + (size_t)n * 20 + hd * 5;
    w[0] = a0 * r;
    w[1] = a1 * r;
    w[2] = a2 * r;
    w[3] = a3 * r;
    w[4] = a4 * r;
}

// ---------- act1 reconstruction: thread per (node, quarter); bf16 act1q + als2/ald2 ----------
__global__ void __launch_bounds__(256) k_act1(const float* __restrict__ xw,
                                              const float* __restrict__ W1,
                                              const float* __restrict__ b1,
                                              const float* __restrict__ vsd2,
                                              unsigned short* __restrict__ act1q,
                                              float* __restrict__ als2,
                                              float* __restrict__ ald2) {
    int t = blockIdx.x * blockDim.x + threadIdx.x;
    if (t >= NN * 4) return;
    int n = t >> 2, q = t & 3;
    int c0 = q * 32;
    const float* w = xw + (size_t)n * 20 + q * 5;  // act1 head q only needs its 5 weights
    float w0 = w[0], w1 = w[1], w2 = w[2], w3 = w[3], w4 = w[4];
    float pS0 = 0.f, pS1 = 0.f, pD0 = 0.f, pD1 = 0.f;
    unsigned short outv[32];
#pragma unroll
    for (int k = 0; k < 32; k++) {
        int ch = c0 + k;
        float v = w0 * W1[ch] + w1 * W1[128 + ch] + w2 * W1[256 + ch] +
                  w3 * W1[384 + ch] + w4 * W1[512 + ch] + b1[ch];
        v = elu1(v);
        outv[k] = (unsigned short)bf16rne(v);
        pS0 += v * vsd2[ch];
        pS1 += v * vsd2[128 + ch];
        pD0 += v * vsd2[256 + ch];
        pD1 += v * vsd2[384 + ch];
    }
    ushort4* dst = (ushort4*)(act1q + (size_t)n * 128 + c0);
#pragma unroll
    for (int k = 0; k < 8; k++)
        dst[k] = make_ushort4(outv[4 * k], outv[4 * k + 1], outv[4 * k + 2], outv[4 * k + 3]);
    pS0 += __shfl_xor(pS0, 1); pS0 += __shfl_xor(pS0, 2);
    pS1 += __shfl_xor(pS1, 1); pS1 += __shfl_xor(pS1, 2);
    pD0 += __shfl_xor(pD0, 1); pD0 += __shfl_xor(pD0, 2);
    pD1 += __shfl_xor(pD1, 1); pD1 += __shfl_xor(pD1, 2);
    if (q == 0) {
        als2[n * 2] = pS0;
        als2[n * 2 + 1] = pS1;
        ald2[n * 2] = pD0;
        ald2[n * 2 + 1] = pD1;
    }
}

// ---------- h2 = act1 @ W2 via MFMA bf16: wave = 16 nodes x 32 cols ----------
// A frag: A[m=lane&15][k=quad*8+j]; B frag: B[k=quad*8+j][n=lane&15] (col-major W2q);
// C/D: col=lane&15, row=quad*4+reg  [verified layouts: learn_hip m89/m120]
__global__ void __launch_bounds__(256) k_gemm2(const unsigned short* __restrict__ act1q,
                                               const unsigned short* __restrict__ W2q,
                                               unsigned short* __restrict__ h2q) {
    int wid = (blockIdx.x * blockDim.x + threadIdx.x) >> 6;  // 12500 waves exactly
    int lane = threadIdx.x & 63;
    int mt = wid >> 1, jh = wid & 1;
    int n0 = mt * 16;                 // NN = 6250*16 exactly, no masking
    int m = lane & 15, quad = lane >> 4;
    int jA = jh * 32;
    const bf16x8* Ab = (const bf16x8*)(act1q + (size_t)(n0 + m) * 128 + quad * 8);
    const bf16x8* B0 = (const bf16x8*)(W2q + (size_t)(jA + m) * 128 + quad * 8);
    const bf16x8* B1 = (const bf16x8*)(W2q + (size_t)(jA + 16 + m) * 128 + quad * 8);
    f32x4 acc0 = {0.f, 0.f, 0.f, 0.f}, acc1 = {0.f, 0.f, 0.f, 0.f};
#pragma unroll
    for (int kc = 0; kc < 4; kc++) {   // +32 ushorts = +4 bf16x8 units
        bf16x8 a = Ab[kc * 4];
        bf16x8 b0 = B0[kc * 4];
        bf16x8 b1 = B1[kc * 4];
        acc0 = __builtin_amdgcn_mfma_f32_16x16x32_bf16(a, b0, acc0, 0, 0, 0);
        acc1 = __builtin_amdgcn_mfma_f32_16x16x32_bf16(a, b1, acc1, 0, 0, 0);
    }
#pragma unroll
    for (int r = 0; r < 4; r++) {
        int node = n0 + quad * 4 + r;
        h2q[(size_t)node * 64 + jA + m] = (unsigned short)bf16rne(acc0[r]);
        h2q[(size_t)node * 64 + jA + 16 + m] = (unsigned short)bf16rne(acc1[r]);
    }
}

// ---------- layer 2 agg: thread per (node, head-half); single pass, m = aself ----------
__global__ void k_agg2(const int* __restrict__ rowptr, const uint2* __restrict__ edges,
                       const unsigned short* __restrict__ h2q,
                       const float* __restrict__ als2, const float* __restrict__ ald2,
                       const float* __restrict__ la, const float* __restrict__ me,
                       const float* __restrict__ b2, const float* __restrict__ W3,
                       float* __restrict__ h3) {
    int t = blockIdx.x * blockDim.x + threadIdx.x;
    if (t >= NN * 4) return;
    int n = t >> 2, sub = t & 3, hd = sub >> 1, qh = sub & 1;
    int cbase = hd * 32 + qh * 16;
    float me0 = me[hd], me1 = me[2 + hd];
    float aldn = ald2[n * 2 + hd];
    float aself = lrelu(als2[n * 2 + hd] + aldn + la[2 * n] * me0 + la[2 * n + 1] * me1);
    int start = rowptr[n], end = rowptr[n + 1];
    float den = 1.f;
    float acc[16];
    {
        const uint4* hp = (const uint4*)(h2q + (size_t)n * 64 + cbase);
        uint4 u0 = hp[0], u1 = hp[1];
        acc[0] = bf16lo(u0.x); acc[1] = bf16hi(u0.x);
        acc[2] = bf16lo(u0.y); acc[3] = bf16hi(u0.y);
        acc[4] = bf16lo(u0.z); acc[5] = bf16hi(u0.z);
        acc[6] = bf16lo(u0.w); acc[7] = bf16hi(u0.w);
        acc[8] = bf16lo(u1.x); acc[9] = bf16hi(u1.x);
        acc[10] = bf16lo(u1.y); acc[11] = bf16hi(u1.y);
        acc[12] = bf16lo(u1.z); acc[13] = bf16hi(u1.z);
        acc[14] = bf16lo(u1.w); acc[15] = bf16hi(u1.w);
    }
    for (int e = start; e < end; ++e) {
        uint2 ep = edges[e];
        int s = (int)ep.x;
        float a = lrelu(als2[s * 2 + hd] + aldn + bf16lo(ep.y) * me0 + bf16hi(ep.y) * me1);
        float p = fexp2(a - aself);
        den += p;
        const uint4* sp = (const uint4*)(h2q + (size_t)s * 64 + cbase);
        uint4 u0 = sp[0], u1 = sp[1];
        acc[0] += p * bf16lo(u0.x); acc[1] += p * bf16hi(u0.x);
        acc[2] += p * bf16lo(u0.y); acc[3] += p * bf16hi(u0.y);
        acc[4] += p * bf16lo(u0.z); acc[5] += p * bf16hi(u0.z);
        acc[6] += p * bf16lo(u0.w); acc[7] += p * bf16hi(u0.w);
        acc[8] += p * bf16lo(u1.x); acc[9] += p * bf16hi(u1.x);
        acc[10] += p * bf16lo(u1.y); acc[11] += p * bf16hi(u1.y);
        acc[12] += p * bf16lo(u1.z); acc[13] += p * bf16hi(u1.z);
        acc[14] += p * bf16lo(u1.w); acc[15] += p * bf16hi(u1.w);
    }
    float r = 1.f / den;
    float part = 0.f;
#pragma unroll
    for (int c = 0; c < 16; c++) {
        float v = elu1(acc[c] * r + b2[cbase + c]);
        part += v * W3[cbase + c];
    }
    part += __shfl_xor(part, 1);
    part += __shfl_xor(part, 2);
    if (sub == 0) h3[n] = part;
}

// ---------- layer 3 agg: wave per node, lanes over edges; m = aself ----------
__global__ void k_agg3(const int* __restrict__ rowptr, const uint2* __restrict__ edges,
                       const float* __restrict__ h, const float* __restrict__ aS3,
                       const float* __restrict__ aD3, const float* __restrict__ la,
                       const float* __restrict__ me, const float* __restrict__ b,
                       float* __restrict__ out) {
    int n = (blockIdx.x * blockDim.x + threadIdx.x) >> 6;
    if (n >= NN) return;
    int lane = threadIdx.x & 63;
    float me0 = me[0], me1 = me[1];
    float aSs = aS3[0] * LOG2E, aDs = aD3[0] * LOG2E;
    float hn = h[n];
    float ald_n = hn * aDs;
    float aself = lrelu(hn * aSs + ald_n + la[2 * n] * me0 + la[2 * n + 1] * me1);
    int start = rowptr[n], end = rowptr[n + 1];
    float den = 0.f, num = 0.f;
    for (int e = start + lane; e < end; e += 64) {
        uint2 ep = edges[e];
        int s = (int)ep.x;
        float hv = h[s];
        float a = lrelu(hv * aSs + ald_n + bf16lo(ep.y) * me0 + bf16hi(ep.y) * me1);
        float p = fexp2(a - aself);
        den += p;
        num += p * hv;
    }
#pragma unroll
    for (int off = 32; off > 0; off >>= 1) {
        den += __shfl_xor(den, off);
        num += __shfl_xor(num, off);
    }
    if (lane == 0) {
        den += 1.f;
        num += hn;
        float v = num / den + b[0];
        out[n] = 1.f / (1.f + __expf(-v));
    }
}

extern "C" void kernel_launch(void* const* d_in, const int* in_sizes, int n_in,
                              void* d_out, int out_size, void* d_ws, size_t ws_size,
                              hipStream_t stream) {
    const float* x   = (const float*)d_in[0];
    const int*   ei  = (const int*)d_in[1];
    const float* ea  = (const float*)d_in[2];
    const float* W1  = (const float*)d_in[3];
    const float* aS1 = (const float*)d_in[4];
    const float* aD1 = (const float*)d_in[5];
    const float* We1 = (const float*)d_in[6];
    const float* aE1 = (const float*)d_in[7];
    const float* b1  = (const float*)d_in[8];
    const float* W2  = (const float*)d_in[9];
    const float* aS2 = (const float*)d_in[10];
    const float* aD2 = (const float*)d_in[11];
    const float* We2 = (const float*)d_in[12];
    const float* aE2 = (const float*)d_in[13];
    const float* b2  = (const float*)d_in[14];
    const float* W3  = (const float*)d_in[15];
    const float* aS3 = (const float*)d_in[16];
    const float* aD3 = (const float*)d_in[17];
    const float* We3 = (const float*)d_in[18];
    const float* aE3 = (const float*)d_in[19];
    const float* b3  = (const float*)d_in[20];

    const int* srcv = ei;
    const int* dstv = ei + NE;

    char* basep = (char*)d_ws;
    size_t off = 0;
    auto alloc = [&](size_t nbytes) -> void* {
        void* p = basep + off;
        off += (nbytes + 255) & ~(size_t)255;
        return p;
    };
    int*    bucket_cnt  = (int*)alloc((size_t)(NB + 1) * 4);
    int*    bucket_base = (int*)alloc((size_t)(NB + 1) * 4);
    int*    rowptr      = (int*)alloc((size_t)(NN + 1) * 4);
    int*    seg         = (int*)alloc((size_t)NCHUNK * SEGW * 4);
    uint2*  binned      = (uint2*)alloc((size_t)NE * 8);
    unsigned char* dstb = (unsigned char*)alloc((size_t)NE);
    uint2*  edges       = (uint2*)alloc((size_t)NE * 8);
    float*  la          = (float*)alloc((size_t)NN * 8);
    float*  cbuf        = (float*)alloc(256);   // me1[0..7], me2[8..11], me3[12..13], vsd[16..55]
    float*  vsd2        = (float*)alloc(2048);  // vS2[2][128], vD2[2][128]
    unsigned short* W2q = (unsigned short*)alloc(64 * 128 * 2);
    float4* xp          = (float4*)alloc((size_t)NN * 32);
    float4* als1        = (float4*)alloc((size_t)NN * 16);
    float4* ald1        = (float4*)alloc((size_t)NN * 16);
    float*  xw          = (float*)alloc((size_t)NN * 80);
    unsigned short* act1q = (unsigned short*)alloc((size_t)NN * 256);
    unsigned short* h2q = (unsigned short*)alloc((size_t)NN * 128);
    float*  als2        = (float*)alloc((size_t)NN * 8);
    float*  ald2        = (float*)alloc((size_t)NN * 8);
    float*  h3          = (float*)alloc((size_t)NN * 4);
    (void)ws_size; (void)in_sizes; (void)n_in; (void)out_size;

    float* me1 = cbuf;
    float* me2 = cbuf + 8;
    float* me3 = cbuf + 12;
    float* vsd = cbuf + 16;

    auto cdiv = [](long long a, long long b) { return (int)((a + b - 1) / b); };
    const int BS = 256;

    // ---- binned CSR build (chunk-major staged; zero scattered global writes) ----
    hipMemsetAsync(bucket_cnt, 0, (size_t)(NB + 1) * 4, stream);
    k_bin1<<<NCHUNK, 256, 0, stream>>>(srcv, dstv, ea, bucket_cnt, seg, binned, dstb);
    k_bscan<<<1, 512, 0, stream>>>(bucket_cnt, bucket_base);
    k_bin2<<<NB, 256, 0, stream>>>(bucket_base, seg, binned, dstb, rowptr, edges, la);

    // ---- tiny constants ----
    k_const<<<1, 64, 0, stream>>>(We1, aE1, We2, aE2, We3, aE3, W1, aS1, aD1, cbuf);
    k_const2<<<1, 256, 0, stream>>>(W2, aS2, aD2, W2q, vsd2);

    // ================= Layer 1: IN=5, H=4, C=32 (ELU) =================
    k_prep1<<<cdiv(NN, BS), BS, 0, stream>>>(x, vsd, xp, als1, ald1);
    k_agg1<<<cdiv((long long)NN * 4, BS), BS, 0, stream>>>(rowptr, edges, xp,
                                                           (const float*)als1,
                                                           (const float*)ald1, la, me1, xw);

    // ================= Layer 2: IN=128, H=2, C=32 (ELU) =================
    k_act1<<<cdiv((long long)NN * 4, BS), BS, 0, stream>>>(xw, W1, b1, vsd2, act1q,
                                                           als2, ald2);
    k_gemm2<<<3125, 256, 0, stream>>>(act1q, W2q, h2q);  // 12500 waves exactly
    k_agg2<<<cdiv((long long)NN * 4, BS), BS, 0, stream>>>(rowptr, edges, h2q, als2, ald2,
                                                           la, me2, b2, W3, h3);

    // ================= Layer 3: IN=64, H=1, C=1 (sigmoid) =================
    k_agg3<<<cdiv(NN, 4), 256, 0, stream>>>(rowptr, edges, h3, aS3, aD3, la, me3,
                                            b3, (float*)d_out);
}

// Round 15
// 344.946 us; speedup vs baseline: 1.1397x; 1.1397x over previous
//
#include <hip/hip_runtime.h>
#include <math.h>

#define NN 100000
#define NE 1600000
#define NPB 256                     // nodes per bucket (dst >> 8)
#define NB 391                      // ceil(NN / NPB)
#define NCHUNK 512                  // binning chunks
#define CH 3125                     // NE / NCHUNK (exact)
#define SEGW (NB + 1)               // seg table row width
#define MAXB 5376                   // max records per bucket (mean 4096, +20 sigma)
#define LOG2E 1.44269504088896f

typedef __attribute__((ext_vector_type(8))) short bf16x8;
typedef __attribute__((ext_vector_type(4))) float f32x4;

__device__ __forceinline__ float lrelu(float x) { return fmaxf(x, 0.2f * x); }
__device__ __forceinline__ float elu1(float x) { return x > 0.f ? x : (__expf(x) - 1.f); }
__device__ __forceinline__ float fexp2(float x) {
#if __has_builtin(__builtin_amdgcn_exp2f)
    return __builtin_amdgcn_exp2f(x);
#else
    return exp2f(x);
#endif
}
__device__ __forceinline__ unsigned bf16rne(float f) {
    unsigned u = __float_as_uint(f);
    return (u + 0x7FFFu + ((u >> 16) & 1u)) >> 16;
}
__device__ __forceinline__ float bf16lo(unsigned u) { return __uint_as_float(u << 16); }
__device__ __forceinline__ float bf16hi(unsigned u) {
    return __uint_as_float(u & 0xFFFF0000u);
}

// ================= binned CSR build =================
__global__ void __launch_bounds__(256) k_bin1(const int* __restrict__ src,
                                              const int* __restrict__ dst,
                                              const float* __restrict__ ea,
                                              int* __restrict__ bucket_cnt,
                                              int* __restrict__ seg,
                                              uint2* __restrict__ binned,
                                              unsigned char* __restrict__ dstb) {
    __shared__ int hist[NB], start[NB], cur[NB];
    __shared__ int s2[256];
    __shared__ uint2 stage[CH];
    __shared__ unsigned char dstg[CH];
    int c = blockIdx.x, t = threadIdx.x;
    int e0 = c * CH;
    for (int b = t; b < NB; b += 256) hist[b] = 0;
    __syncthreads();
    for (int i = t; i < CH; i += 256) atomicAdd(&hist[dst[e0 + i] >> 8], 1);
    __syncthreads();
    int a0 = (2 * t < NB) ? hist[2 * t] : 0;
    int a1 = (2 * t + 1 < NB) ? hist[2 * t + 1] : 0;
    s2[t] = a0 + a1;
    __syncthreads();
    for (int off = 1; off < 256; off <<= 1) {
        int x = (t >= off) ? s2[t - off] : 0;
        __syncthreads();
        if (t >= off) s2[t] += x;
        __syncthreads();
    }
    int pex = s2[t] - (a0 + a1);
    if (2 * t < NB) { start[2 * t] = pex; cur[2 * t] = pex; }
    if (2 * t + 1 < NB) { start[2 * t + 1] = pex + a0; cur[2 * t + 1] = pex + a0; }
    __syncthreads();
    for (int b = t; b < NB; b += 256) {
        seg[c * SEGW + b] = start[b];
        if (hist[b]) atomicAdd(&bucket_cnt[b], hist[b]);
    }
    if (t == 0) seg[c * SEGW + NB] = CH;
    __syncthreads();
    for (int i = t; i < CH; i += 256) {
        int d = dst[e0 + i];
        int bkt = d >> 8;
        int p = atomicAdd(&cur[bkt], 1);
        unsigned pk = bf16rne(ea[2 * (e0 + i)]) | (bf16rne(ea[2 * (e0 + i) + 1]) << 16);
        stage[p] = make_uint2((unsigned)src[e0 + i], pk);
        dstg[p] = (unsigned char)(d & 255);
    }
    __syncthreads();
    for (int i = t; i < CH; i += 256) {
        binned[e0 + i] = stage[i];
        dstb[e0 + i] = dstg[i];
    }
}

__global__ void k_bscan(const int* __restrict__ bucket_cnt, int* __restrict__ bucket_base) {
    __shared__ int s[512];
    int t = threadIdx.x;
    int v = (t < NB) ? bucket_cnt[t] : 0;
    s[t] = v;
    __syncthreads();
    for (int off = 1; off < 512; off <<= 1) {
        int x = (t >= off) ? s[t - off] : 0;
        __syncthreads();
        if (t >= off) s[t] += x;
        __syncthreads();
    }
    if (t < NB) {
        bucket_base[t] = s[t] - v;
        if (t == NB - 1) bucket_base[NB] = s[t];
    }
}

__global__ void __launch_bounds__(256) k_bin2(const int* __restrict__ bucket_base,
                                              const int* __restrict__ seg,
                                              const uint2* __restrict__ binned,
                                              const unsigned char* __restrict__ dstb,
                                              int* __restrict__ rowptr,
                                              uint2* __restrict__ edges,
                                              float* __restrict__ la) {
    __shared__ int sstart[NCHUNK], soff[NCHUNK];
    __shared__ int s2[256];
    __shared__ uint2 stage[MAXB];
    __shared__ unsigned char sd[MAXB];
    __shared__ int hist[NPB], pre[NPB], cursor[NPB];
    __shared__ float ea0s[NPB], ea1s[NPB];
    int b = blockIdx.x, t = threadIdx.x;
    int len0, len1;
    {
        int c0 = 2 * t, c1 = 2 * t + 1;
        int st0 = seg[c0 * SEGW + b], en0 = seg[c0 * SEGW + b + 1];
        int st1 = seg[c1 * SEGW + b], en1 = seg[c1 * SEGW + b + 1];
        sstart[c0] = st0;
        sstart[c1] = st1;
        len0 = en0 - st0;
        len1 = en1 - st1;
        s2[t] = len0 + len1;
    }
    __syncthreads();
    for (int off = 1; off < 256; off <<= 1) {
        int x = (t >= off) ? s2[t - off] : 0;
        __syncthreads();
        if (t >= off) s2[t] += x;
        __syncthreads();
    }
    int pex = s2[t] - (len0 + len1);
    soff[2 * t] = pex;
    soff[2 * t + 1] = pex + len0;
    __syncthreads();
    int total = s2[255];
    if (total > MAXB) total = MAXB;
    for (int i = t; i < total; i += 256) {
        int lo = 0, hi = NCHUNK - 1;
        while (lo < hi) {
            int mid = (lo + hi + 1) >> 1;
            if (soff[mid] <= i) lo = mid; else hi = mid - 1;
        }
        int pos = lo * CH + sstart[lo] + (i - soff[lo]);
        stage[i] = binned[pos];
        sd[i] = dstb[pos];
    }
    hist[t] = 0;
    ea0s[t] = 0.f;
    ea1s[t] = 0.f;
    __syncthreads();
    for (int i = t; i < total; i += 256) atomicAdd(&hist[sd[i]], 1);
    __syncthreads();
    int v = hist[t];
    pre[t] = v;
    __syncthreads();
    for (int off = 1; off < 256; off <<= 1) {
        int x = (t >= off) ? pre[t - off] : 0;
        __syncthreads();
        if (t >= off) pre[t] += x;
        __syncthreads();
    }
    int bb = bucket_base[b];
    int ex = pre[t] - v;
    int nb0 = b << 8;
    if (nb0 + t <= NN) rowptr[nb0 + t] = bb + ex;
    cursor[t] = bb + ex;
    __syncthreads();
    for (int i = t; i < total; i += 256) {
        uint2 rec = stage[i];
        unsigned char d = sd[i];
        int pos = atomicAdd(&cursor[d], 1);
        edges[pos] = rec;
        atomicAdd(&ea0s[d], bf16lo(rec.y));
        atomicAdd(&ea1s[d], bf16hi(rec.y));
    }
    __syncthreads();
    int n = nb0 + t;
    if (n < NN) {
        float dg = fmaxf((float)v, 1.0f);
        la[2 * n] = ea0s[t] / dg;
        la[2 * n + 1] = ea1s[t] / dg;
    }
}

// ---------- constants: block 0 -> cbuf; blocks 1..8 -> W2q; block 9 -> vsd2 ----------
__global__ void k_const(const float* __restrict__ We1, const float* __restrict__ aE1,
                        const float* __restrict__ We2, const float* __restrict__ aE2,
                        const float* __restrict__ We3, const float* __restrict__ aE3,
                        const float* __restrict__ W1, const float* __restrict__ aS1,
                        const float* __restrict__ aD1, const float* __restrict__ W2,
                        const float* __restrict__ aS2, const float* __restrict__ aD2,
                        float* __restrict__ cbuf, unsigned short* __restrict__ W2q,
                        float* __restrict__ vsd2) {
    int t = threadIdx.x;
    if (blockIdx.x == 0) {
        if (t < 8) {
            int d = t >> 2, hd = t & 3;
            float s = 0.f;
            for (int c = 0; c < 32; c++) s += We1[d * 128 + hd * 32 + c] * aE1[hd * 32 + c];
            cbuf[t] = s * LOG2E;
        } else if (t < 12) {
            int idx = t - 8, d = idx >> 1, hd = idx & 1;
            float s = 0.f;
            for (int c = 0; c < 32; c++) s += We2[d * 64 + hd * 32 + c] * aE2[hd * 32 + c];
            cbuf[t] = s * LOG2E;
        } else if (t < 14) {
            cbuf[t] = We3[t - 12] * aE3[0] * LOG2E;
        } else if (t >= 16 && t < 56) {
            int r = (t - 16) % 20, hd = r / 5, i = r % 5;
            const float* a = (t - 16 < 20) ? aS1 : aD1;
            float s = 0.f;
            for (int c = 0; c < 32; c++) s += W1[i * 128 + hd * 32 + c] * a[hd * 32 + c];
            cbuf[t] = s * LOG2E;
        }
    } else if (blockIdx.x <= 8) {
#pragma unroll
        for (int i = 0; i < 4; i++) {
            int x = (blockIdx.x - 1) * 1024 + i * 256 + t;
            int j = x >> 7, ii = x & 127;
            W2q[x] = (unsigned short)bf16rne(W2[ii * 64 + j]);  // W2q[j][i] col-major
        }
    } else {
        // vsd2: vS2[hd][i] = sum_c W2[i, hd*32+c]*aS2[hd,c] (scaled); vD2 at +256
        int hd = t >> 7, i = t & 127;
        float s = 0.f, d = 0.f;
        for (int c = 0; c < 32; c++) {
            float wv = W2[i * 64 + hd * 32 + c];
            s += wv * aS2[hd * 32 + c];
            d += wv * aD2[hd * 32 + c];
        }
        vsd2[t] = s * LOG2E;
        vsd2[256 + t] = d * LOG2E;
    }
}

// layer-1 per-node: padded x + logits als1/ald1 (scaled)
__global__ void k_prep1(const float* __restrict__ x, const float* __restrict__ vsd,
                        float4* __restrict__ xp, float4* __restrict__ als1,
                        float4* __restrict__ ald1) {
    int n = blockIdx.x * blockDim.x + threadIdx.x;
    if (n >= NN) return;
    float x0 = x[5 * n], x1 = x[5 * n + 1], x2 = x[5 * n + 2], x3 = x[5 * n + 3],
          x4 = x[5 * n + 4];
    xp[2 * n] = make_float4(x0, x1, x2, x3);
    xp[2 * n + 1] = make_float4(x4, 0.f, 0.f, 0.f);
    float sv[4], dv[4];
#pragma unroll
    for (int hd = 0; hd < 4; hd++) {
        const float* vS = vsd + hd * 5;
        const float* vD = vsd + 20 + hd * 5;
        sv[hd] = x0 * vS[0] + x1 * vS[1] + x2 * vS[2] + x3 * vS[3] + x4 * vS[4];
        dv[hd] = x0 * vD[0] + x1 * vD[1] + x2 * vD[2] + x3 * vD[3] + x4 * vD[4];
    }
    als1[n] = make_float4(sv[0], sv[1], sv[2], sv[3]);
    ald1[n] = make_float4(dv[0], dv[1], dv[2], dv[3]);
}

// ---------- layer 1 agg: thread per (node, head); single pass, m = aself ----------
__global__ void k_agg1(const int* __restrict__ rowptr, const uint2* __restrict__ edges,
                       const float4* __restrict__ xp, const float* __restrict__ als1,
                       const float* __restrict__ ald1, const float* __restrict__ la,
                       const float* __restrict__ me, float* __restrict__ xw) {
    int t = blockIdx.x * blockDim.x + threadIdx.x;
    if (t >= NN * 4) return;
    int n = t >> 2, hd = t & 3;
    float me0 = me[hd], me1 = me[4 + hd];
    float aldn = ald1[t];
    float aself = lrelu(als1[t] + aldn + la[2 * n] * me0 + la[2 * n + 1] * me1);
    int start = rowptr[n], end = rowptr[n + 1];
    float den = 1.f;
    float4 xa = xp[2 * n];
    float xb = xp[2 * n + 1].x;
    float a0 = xa.x, a1 = xa.y, a2 = xa.z, a3 = xa.w, a4 = xb;
    for (int e = start; e < end; ++e) {
        uint2 ep = edges[e];
        int s = (int)ep.x;
        float a = lrelu(als1[s * 4 + hd] + aldn + bf16lo(ep.y) * me0 + bf16hi(ep.y) * me1);
        float p = fexp2(a - aself);
        den += p;
        float4 sa = xp[2 * s];
        float sb = xp[2 * s + 1].x;
        a0 += p * sa.x;
        a1 += p * sa.y;
        a2 += p * sa.z;
        a3 += p * sa.w;
        a4 += p * sb;
    }
    float r = 1.f / den;
    float* w = xw + (size_t)n * 20 + hd * 5;
    w[0] = a0 * r;
    w[1] = a1 * r;
    w[2] = a2 * r;
    w[3] = a3 * r;
    w[4] = a4 * r;
}

// ---------- layer 2 fused: act1 -> LDS (bf16) -> MFMA h2; als2/ald2 from f32 act1 ----------
// 64 nodes/block, 256 threads. Phase 2: wave `wid` owns node-group wid (16 nodes)
// and iterates ALL 4 column-groups (R13/R14 bug: only half the nodes were covered).
__global__ void __launch_bounds__(256) k_l2fused(
        const float* __restrict__ xw, const float* __restrict__ W1,
        const float* __restrict__ b1, const unsigned short* __restrict__ W2q,
        const float* __restrict__ vsd2, unsigned short* __restrict__ h2q,
        float* __restrict__ als2, float* __restrict__ ald2) {
    __shared__ unsigned short sact[64 * 136];
    __shared__ float sW1[640], sb1[128], sv2[512];
    int t = threadIdx.x;
    int nb = blockIdx.x * 64;
    for (int i = t; i < 640; i += 256) sW1[i] = W1[i];
    for (int i = t; i < 512; i += 256) sv2[i] = vsd2[i];
    if (t < 128) sb1[t] = b1[t];
    __syncthreads();
    // phase 1: thread = (node, quarter); 32 channels; f32 logit partials + bf16 store
    {
        int nl = t >> 2, q = t & 3;
        int node = nb + nl;
        float w0 = 0.f, w1 = 0.f, w2 = 0.f, w3 = 0.f, w4 = 0.f;
        if (node < NN) {
            const float* w = xw + (size_t)node * 20 + q * 5;
            w0 = w[0]; w1 = w[1]; w2 = w[2]; w3 = w[3]; w4 = w[4];
        }
        int c0 = q * 32;
        unsigned* dst = (unsigned*)(sact + nl * 136 + c0);
        float pS0 = 0.f, pS1 = 0.f, pD0 = 0.f, pD1 = 0.f;
#pragma unroll
        for (int k = 0; k < 32; k += 2) {
            int ch = c0 + k;
            float v0 = w0 * sW1[ch] + w1 * sW1[128 + ch] + w2 * sW1[256 + ch] +
                       w3 * sW1[384 + ch] + w4 * sW1[512 + ch] + sb1[ch];
            float v1 = w0 * sW1[ch + 1] + w1 * sW1[129 + ch] + w2 * sW1[257 + ch] +
                       w3 * sW1[385 + ch] + w4 * sW1[513 + ch] + sb1[ch + 1];
            v0 = (node < NN) ? elu1(v0) : 0.f;
            v1 = (node < NN) ? elu1(v1) : 0.f;
            pS0 += v0 * sv2[ch];
            pS0 += v1 * sv2[ch + 1];
            pS1 += v0 * sv2[128 + ch];
            pS1 += v1 * sv2[129 + ch];
            pD0 += v0 * sv2[256 + ch];
            pD0 += v1 * sv2[257 + ch];
            pD1 += v0 * sv2[384 + ch];
            pD1 += v1 * sv2[385 + ch];
            dst[k >> 1] = bf16rne(v0) | (bf16rne(v1) << 16);
        }
        // reduce over the 4 quarter-threads (adjacent lanes)
        pS0 += __shfl_xor(pS0, 1); pS0 += __shfl_xor(pS0, 2);
        pS1 += __shfl_xor(pS1, 1); pS1 += __shfl_xor(pS1, 2);
        pD0 += __shfl_xor(pD0, 1); pD0 += __shfl_xor(pD0, 2);
        pD1 += __shfl_xor(pD1, 1); pD1 += __shfl_xor(pD1, 2);
        if (q == 0 && node < NN) {
            als2[node * 2] = pS0;
            als2[node * 2 + 1] = pS1;
            ald2[node * 2] = pD0;
            ald2[node * 2 + 1] = pD1;
        }
    }
    __syncthreads();
    // phase 2: wave wid -> node rows wid*16..wid*16+15; all 4 col-groups of 16
    int wid = t >> 6, lane = t & 63;
    int m = lane & 15, quad = lane >> 4;
    int nrow = wid * 16 + m;
    const bf16x8* Ab = (const bf16x8*)(sact + nrow * 136 + quad * 8);
    bf16x8 a[4];
#pragma unroll
    for (int kc = 0; kc < 4; kc++) a[kc] = Ab[kc * 4];
#pragma unroll
    for (int jg = 0; jg < 4; jg++) {
        const bf16x8* B = (const bf16x8*)(W2q + (size_t)(jg * 16 + m) * 128 + quad * 8);
        f32x4 acc = {0.f, 0.f, 0.f, 0.f};
#pragma unroll
        for (int kc = 0; kc < 4; kc++)
            acc = __builtin_amdgcn_mfma_f32_16x16x32_bf16(a[kc], B[kc * 4], acc, 0, 0, 0);
#pragma unroll
        for (int r = 0; r < 4; r++) {
            int node = nb + wid * 16 + quad * 4 + r;
            if (node < NN)
                h2q[(size_t)node * 64 + jg * 16 + m] = (unsigned short)bf16rne(acc[r]);
        }
    }
}

// ---------- layer 2 agg: thread per (node, head-half); single pass, m = aself ----------
__global__ void k_agg2(const int* __restrict__ rowptr, const uint2* __restrict__ edges,
                       const unsigned short* __restrict__ h2q,
                       const float* __restrict__ als2, const float* __restrict__ ald2,
                       const float* __restrict__ la, const float* __restrict__ me,
                       const float* __restrict__ b2, const float* __restrict__ W3,
                       float* __restrict__ h3) {
    int t = blockIdx.x * blockDim.x + threadIdx.x;
    if (t >= NN * 4) return;
    int n = t >> 2, sub = t & 3, hd = sub >> 1, qh = sub & 1;
    int cbase = hd * 32 + qh * 16;
    float me0 = me[hd], me1 = me[2 + hd];
    float aldn = ald2[n * 2 + hd];
    float aself = lrelu(als2[n * 2 + hd] + aldn + la[2 * n] * me0 + la[2 * n + 1] * me1);
    int start = rowptr[n], end = rowptr[n + 1];
    float den = 1.f;
    float acc[16];
    {
        const uint4* hp = (const uint4*)(h2q + (size_t)n * 64 + cbase);
        uint4 u0 = hp[0], u1 = hp[1];
        acc[0] = bf16lo(u0.x); acc[1] = bf16hi(u0.x);
        acc[2] = bf16lo(u0.y); acc[3] = bf16hi(u0.y);
        acc[4] = bf16lo(u0.z); acc[5] = bf16hi(u0.z);
        acc[6] = bf16lo(u0.w); acc[7] = bf16hi(u0.w);
        acc[8] = bf16lo(u1.x); acc[9] = bf16hi(u1.x);
        acc[10] = bf16lo(u1.y); acc[11] = bf16hi(u1.y);
        acc[12] = bf16lo(u1.z); acc[13] = bf16hi(u1.z);
        acc[14] = bf16lo(u1.w); acc[15] = bf16hi(u1.w);
    }
    for (int e = start; e < end; ++e) {
        uint2 ep = edges[e];
        int s = (int)ep.x;
        float a = lrelu(als2[s * 2 + hd] + aldn + bf16lo(ep.y) * me0 + bf16hi(ep.y) * me1);
        float p = fexp2(a - aself);
        den += p;
        const uint4* sp = (const uint4*)(h2q + (size_t)s * 64 + cbase);
        uint4 u0 = sp[0], u1 = sp[1];
        acc[0] += p * bf16lo(u0.x); acc[1] += p * bf16hi(u0.x);
        acc[2] += p * bf16lo(u0.y); acc[3] += p * bf16hi(u0.y);
        acc[4] += p * bf16lo(u0.z); acc[5] += p * bf16hi(u0.z);
        acc[6] += p * bf16lo(u0.w); acc[7] += p * bf16hi(u0.w);
        acc[8] += p * bf16lo(u1.x); acc[9] += p * bf16hi(u1.x);
        acc[10] += p * bf16lo(u1.y); acc[11] += p * bf16hi(u1.y);
        acc[12] += p * bf16lo(u1.z); acc[13] += p * bf16hi(u1.z);
        acc[14] += p * bf16lo(u1.w); acc[15] += p * bf16hi(u1.w);
    }
    float r = 1.f / den;
    float part = 0.f;
#pragma unroll
    for (int c = 0; c < 16; c++) {
        float v = elu1(acc[c] * r + b2[cbase + c]);
        part += v * W3[cbase + c];
    }
    part += __shfl_xor(part, 1);
    part += __shfl_xor(part, 2);
    if (sub == 0) h3[n] = part;
}

// ---------- layer 3 agg: wave per node, lanes over edges; m = aself ----------
__global__ void k_agg3(const int* __restrict__ rowptr, const uint2* __restrict__ edges,
                       const float* __restrict__ h, const float* __restrict__ aS3,
                       const float* __restrict__ aD3, const float* __restrict__ la,
                       const float* __restrict__ me, const float* __restrict__ b,
                       float* __restrict__ out) {
    int n = (blockIdx.x * blockDim.x + threadIdx.x) >> 6;
    if (n >= NN) return;
    int lane = threadIdx.x & 63;
    float me0 = me[0], me1 = me[1];
    float aSs = aS3[0] * LOG2E, aDs = aD3[0] * LOG2E;
    float hn = h[n];
    float ald_n = hn * aDs;
    float aself = lrelu(hn * aSs + ald_n + la[2 * n] * me0 + la[2 * n + 1] * me1);
    int start = rowptr[n], end = rowptr[n + 1];
    float den = 0.f, num = 0.f;
    for (int e = start + lane; e < end; e += 64) {
        uint2 ep = edges[e];
        int s = (int)ep.x;
        float hv = h[s];
        float a = lrelu(hv * aSs + ald_n + bf16lo(ep.y) * me0 + bf16hi(ep.y) * me1);
        float p = fexp2(a - aself);
        den += p;
        num += p * hv;
    }
#pragma unroll
    for (int off = 32; off > 0; off >>= 1) {
        den += __shfl_xor(den, off);
        num += __shfl_xor(num, off);
    }
    if (lane == 0) {
        den += 1.f;
        num += hn;
        float v = num / den + b[0];
        out[n] = 1.f / (1.f + __expf(-v));
    }
}

extern "C" void kernel_launch(void* const* d_in, const int* in_sizes, int n_in,
                              void* d_out, int out_size, void* d_ws, size_t ws_size,
                              hipStream_t stream) {
    const float* x   = (const float*)d_in[0];
    const int*   ei  = (const int*)d_in[1];
    const float* ea  = (const float*)d_in[2];
    const float* W1  = (const float*)d_in[3];
    const float* aS1 = (const float*)d_in[4];
    const float* aD1 = (const float*)d_in[5];
    const float* We1 = (const float*)d_in[6];
    const float* aE1 = (const float*)d_in[7];
    const float* b1  = (const float*)d_in[8];
    const float* W2  = (const float*)d_in[9];
    const float* aS2 = (const float*)d_in[10];
    const float* aD2 = (const float*)d_in[11];
    const float* We2 = (const float*)d_in[12];
    const float* aE2 = (const float*)d_in[13];
    const float* b2  = (const float*)d_in[14];
    const float* W3  = (const float*)d_in[15];
    const float* aS3 = (const float*)d_in[16];
    const float* aD3 = (const float*)d_in[17];
    const float* We3 = (const float*)d_in[18];
    const float* aE3 = (const float*)d_in[19];
    const float* b3  = (const float*)d_in[20];

    const int* srcv = ei;
    const int* dstv = ei + NE;

    char* basep = (char*)d_ws;
    size_t off = 0;
    auto alloc = [&](size_t nbytes) -> void* {
        void* p = basep + off;
        off += (nbytes + 255) & ~(size_t)255;
        return p;
    };
    int*    bucket_cnt  = (int*)alloc((size_t)(NB + 1) * 4);
    int*    bucket_base = (int*)alloc((size_t)(NB + 1) * 4);
    int*    rowptr      = (int*)alloc((size_t)(NN + 1) * 4);
    int*    seg         = (int*)alloc((size_t)NCHUNK * SEGW * 4);
    uint2*  binned      = (uint2*)alloc((size_t)NE * 8);
    unsigned char* dstb = (unsigned char*)alloc((size_t)NE);
    uint2*  edges       = (uint2*)alloc((size_t)NE * 8);
    float*  la          = (float*)alloc((size_t)NN * 8);
    float*  cbuf        = (float*)alloc(256);   // me1[0..7], me2[8..11], me3[12..13], vsd[16..55]
    float*  vsd2        = (float*)alloc(2048);  // vS2[2][128], vD2[2][128]
    unsigned short* W2q = (unsigned short*)alloc(64 * 128 * 2);
    float4* xp          = (float4*)alloc((size_t)NN * 32);
    float4* als1        = (float4*)alloc((size_t)NN * 16);
    float4* ald1        = (float4*)alloc((size_t)NN * 16);
    float*  xw          = (float*)alloc((size_t)NN * 80);
    unsigned short* h2q = (unsigned short*)alloc((size_t)NN * 128);
    float*  als2        = (float*)alloc((size_t)NN * 8);
    float*  ald2        = (float*)alloc((size_t)NN * 8);
    float*  h3          = (float*)alloc((size_t)NN * 4);
    (void)ws_size; (void)in_sizes; (void)n_in; (void)out_size;

    float* me1 = cbuf;
    float* me2 = cbuf + 8;
    float* me3 = cbuf + 12;
    float* vsd = cbuf + 16;

    auto cdiv = [](long long a, long long b) { return (int)((a + b - 1) / b); };
    const int BS = 256;

    // ---- binned CSR build (chunk-major staged; zero scattered global writes) ----
    hipMemsetAsync(bucket_cnt, 0, (size_t)(NB + 1) * 4, stream);
    k_bin1<<<NCHUNK, 256, 0, stream>>>(srcv, dstv, ea, bucket_cnt, seg, binned, dstb);
    k_bscan<<<1, 512, 0, stream>>>(bucket_cnt, bucket_base);
    k_bin2<<<NB, 256, 0, stream>>>(bucket_base, seg, binned, dstb, rowptr, edges, la);

    // ---- constants (cbuf + W2q + vsd2 in one launch) ----
    k_const<<<10, 256, 0, stream>>>(We1, aE1, We2, aE2, We3, aE3, W1, aS1, aD1, W2,
                                    aS2, aD2, cbuf, W2q, vsd2);

    // ================= Layer 1: IN=5, H=4, C=32 (ELU) =================
    k_prep1<<<cdiv(NN, BS), BS, 0, stream>>>(x, vsd, xp, als1, ald1);
    k_agg1<<<cdiv((long long)NN * 4, BS), BS, 0, stream>>>(rowptr, edges, xp,
                                                           (const float*)als1,
                                                           (const float*)ald1, la, me1, xw);

    // ================= Layer 2: IN=128, H=2, C=32 (ELU) =================
    k_l2fused<<<cdiv(NN, 64), 256, 0, stream>>>(xw, W1, b1, W2q, vsd2,
                                                h2q, als2, ald2);
    k_agg2<<<cdiv((long long)NN * 4, BS), BS, 0, stream>>>(rowptr, edges, h2q, als2, ald2,
                                                           la, me2, b2, W3, h3);

    // ================= Layer 3: IN=64, H=1, C=1 (sigmoid) =================
    k_agg3<<<cdiv(NN, 4), 256, 0, stream>>>(rowptr, edges, h3, aS3, aD3, la, me3,
                                            b3, (float*)d_out);
}